// Round 4
// baseline (88.469 us; speedup 1.0000x reference)
//
#include <hip/hip_runtime.h>

#define GDIM 76
#define GG   5776
#define DDIM 85
#define ADIM 3

// Tile = one (b,a,i) row of the transpose, split into two column-halves so
// LDS/block ~14 KB -> 8 blocks/CU (32-wave cap).
//   half 0: columns  0..39 (KV4=10 float4/row), LDSW=41 (41 mod 32 = 9, coprime)
//   half 1: columns 40..75 (KV4= 9 float4/row), LDSW=37 (37 mod 32 = 5, coprime)
// Loads are register-batched (all float4 in flight before compute) for MLP.

template<int KV4, int LDSW, int COLOFF>
__device__ __forceinline__ void process_half(const float* __restrict__ srcb,
                                             float* __restrict__ dstb,
                                             float* lds, int a, int i) {
    const int tid = threadIdx.x;
    constexpr int N4    = DDIM * KV4;           // float4 loads == floats per store-quarter
    constexpr int ITERS = (N4 + 255) / 256;     // 4 (h0) / 3 (h1)

    const float aw  = (a == 0) ? 10.0f : (a == 1) ? 16.0f : 33.0f;
    const float ah  = (a == 0) ? 13.0f : (a == 1) ? 30.0f : 23.0f;
    const float fi8 = (float)i * 8.0f;

    // ---- load phase: batch all global float4 loads into registers ----
    float4 v[ITERS];
    #pragma unroll
    for (int it = 0; it < ITERS; ++it) {
        const int idx = tid + it * 256;
        const int d   = idx / KV4;
        const int k   = idx - d * KV4;
        if (idx < N4)
            v[it] = *(const float4*)(srcb + (size_t)d * GG + 4 * k + COLOFF);
    }

    // ---- activate + LDS write (input layout [d][4k+e], ~2-way write conflicts) ----
    #pragma unroll
    for (int it = 0; it < ITERS; ++it) {
        const int idx = tid + it * 256;
        if (idx < N4) {
            const int d = idx / KV4;
            const int k = idx - d * KV4;
            const bool iswh = (d == 3) | (d == 4);
            const bool isx  = (d == 1);
            const bool isy  = (d == 2);
            const float A   = (d == 3) ? aw : ah;
            const float C   = (isx | isy) ? 8.0f : 1.0f;
            const float Bc  = isx ? fi8 : 0.0f;
            const float g8  = (float)((4 * k + COLOFF) * 8);
            const float vv[4] = {v[it].x, v[it].y, v[it].z, v[it].w};
            float r[4];
            #pragma unroll
            for (int e = 0; e < 4; ++e) {
                const float val = vv[e];
                const float ev  = __expf(iswh ? val : -val);   // one exp/elem
                const float s   = __builtin_amdgcn_rcpf(1.0f + ev);
                const float B   = isy ? (g8 + (float)(8 * e)) : Bc;
                const float rs  = s * C + B;                   // fma
                r[e] = iswh ? ev * A : rs;
            }
            float* p = &lds[d * LDSW + 4 * k];
            p[0] = r[0]; p[1] = r[1]; p[2] = r[2]; p[3] = r[3];
        }
    }
    __syncthreads();

    // ---- store phase: d-invariant quarters (N4 = DDIM*KV4), conflict-free
    //      scalar ds_reads (lane stride LDSW coprime to 32), coalesced stores ----
    #pragma unroll
    for (int it = 0; it < ITERS; ++it) {
        const int f = tid + it * 256;
        if (f < N4) {
            const int j    = f / DDIM;          // local column quarter-index
            const int d    = f - j * DDIM;
            const int base = d * LDSW + j;
            const float t0 = lds[base];
            const float t1 = lds[base + KV4];
            const float t2 = lds[base + 2 * KV4];
            const float t3 = lds[base + 3 * KV4];
            dstb[f]          = t0;
            dstb[f + N4]     = t1;
            dstb[f + 2 * N4] = t2;
            dstb[f + 3 * N4] = t3;
        }
    }
}

__global__ __launch_bounds__(256, 8) void yolo_kernel(const float* __restrict__ x,
                                                      float* __restrict__ out) {
    const int blk  = blockIdx.x;
    const int h    = blk & 1;
    const int pair = blk >> 1;
    const int i    = pair % GDIM;
    const int slab = pair / GDIM;   // b*A + a
    const int a    = slab % ADIM;

    __shared__ float lds[DDIM * 41];   // 13940 B -> 8 blocks/CU (wave-capped)

    const float* srcb = x + (size_t)slab * (DDIM * GG) + i * GDIM;
    float* dstb = out + (size_t)slab * ((size_t)GG * DDIM) + i * (GDIM * DDIM);

    if (h == 0) process_half<10, 41, 0 >(srcb, dstb,             lds, a, i);
    else        process_half< 9, 37, 40>(srcb, dstb + 40 * DDIM, lds, a, i);
}

extern "C" void kernel_launch(void* const* d_in, const int* in_sizes, int n_in,
                              void* d_out, int out_size, void* d_ws, size_t ws_size,
                              hipStream_t stream) {
    const float* x = (const float*)d_in[0];
    float* out = (float*)d_out;
    const int B = in_sizes[0] / (ADIM * DDIM * GG);   // 32
    const int nblocks = B * ADIM * GDIM * 2;          // 14592
    yolo_kernel<<<dim3(nblocks), dim3(256), 0, stream>>>(x, out);
}

// Round 5
// 64.696 us; speedup vs baseline: 1.3675x; 1.3675x over previous
//
#include <hip/hip_runtime.h>

#define GDIM 76
#define GG   5776
#define DDIM 85
#define ADIM 3
#define LDSW 77            // lane stride 77 ≡ 13 (mod 32) -> conflict-free scalar LDS access
#define NV4  1615          // = 19 * 85 = DDIM*GDIM/4
#define ROWV4 19
#define ITERS 7            // 6 full (tid+5*256 <= 1535 < 1615) + 1 tail (tid < 79)

// One block per (b, a, i) slab-row: full 85x76 tile transposed via LDS.
// Round-3 structure (proven conflict-free) + batched static-unrolled loads,
// XCD-aware block swizzle, nontemporal output stores.
__global__ __launch_bounds__(256, 6) void yolo_kernel(const float* __restrict__ x,
                                                      float* __restrict__ out) {
    // XCD swizzle: 7296 = 8 * 912, bijective; each XCD owns 912 consecutive tiles.
    const int cpx = gridDim.x >> 3;                       // 912
    const int blk = (blockIdx.x & 7) * cpx + (blockIdx.x >> 3);

    const int i    = blk % GDIM;
    const int slab = blk / GDIM;   // b*A + a
    const int a    = slab % ADIM;
    const int tid  = threadIdx.x;

    __shared__ float lds[DDIM * LDSW];   // 26180 B -> 6 blocks/CU (24 waves)

    const float aw  = (a == 0) ? 10.0f : (a == 1) ? 16.0f : 33.0f;
    const float ah  = (a == 0) ? 13.0f : (a == 1) ? 30.0f : 23.0f;
    const float fi8 = (float)i * 8.0f;

    const float* __restrict__ src = x + (size_t)slab * (DDIM * GG) + i * GDIM;
    float* __restrict__ dst = out + (size_t)slab * ((size_t)GG * DDIM)
                                  + (size_t)i * (GDIM * DDIM);

    // ---- phase 1a: issue ALL global loads back-to-back (max MLP) ----
    float4 v[ITERS];
    #pragma unroll
    for (int it = 0; it < ITERS; ++it) {
        const int idx = tid + it * 256;
        if (it < 6 || idx < NV4) {
            const int d = idx / ROWV4;                   // magic-mul div by 19
            const int k = idx - d * ROWV4;
            v[it] = *(const float4*)(src + (size_t)d * GG + 4 * k);
        }
    }

    // ---- phase 1b: activation + contiguous LDS writes (~2-way, free) ----
    #pragma unroll
    for (int it = 0; it < ITERS; ++it) {
        const int idx = tid + it * 256;
        if (it < 6 || idx < NV4) {
            const int d = idx / ROWV4;
            const int k = idx - d * ROWV4;
            const bool iswh = (d == 3) | (d == 4);
            const bool isx  = (d == 1);
            const bool isy  = (d == 2);
            const float A   = (d == 3) ? aw : ah;
            const float C   = (isx | isy) ? 8.0f : 1.0f;
            const float Bc  = isx ? fi8 : 0.0f;
            const float gk8 = (float)(4 * k) * 8.0f;
            const float vv[4] = {v[it].x, v[it].y, v[it].z, v[it].w};
            float r[4];
            #pragma unroll
            for (int e = 0; e < 4; ++e) {
                const float val = vv[e];
                const float ev  = __expf(iswh ? val : -val);   // one exp/elem
                const float s   = __builtin_amdgcn_rcpf(1.0f + ev);
                const float B   = isy ? (gk8 + (float)(8 * e)) : Bc;
                const float rs  = s * C + B;                   // fma
                r[e] = iswh ? ev * A : rs;
            }
            float* p = &lds[d * LDSW + 4 * k];
            p[0] = r[0]; p[1] = r[1]; p[2] = r[2]; p[3] = r[3];
        }
    }
    __syncthreads();

    // ---- phase 2a: batch ALL ds_reads (conflict-free: lane stride 77≡13) ----
    float r[ITERS][4];
    #pragma unroll
    for (int it = 0; it < ITERS; ++it) {
        const int t = tid + it * 256;
        if (it < 6 || t < NV4) {
            const int g0   = t / DDIM;                   // magic-mul div by 85
            const int d    = t - g0 * DDIM;
            const int base = d * LDSW + g0;
            r[it][0] = lds[base];
            r[it][1] = lds[base + ROWV4];                // imm offsets 76/152/228 B
            r[it][2] = lds[base + 2 * ROWV4];
            r[it][3] = lds[base + 3 * ROWV4];
        }
    }

    // ---- phase 2b: coalesced nontemporal stores (write-once stream) ----
    #pragma unroll
    for (int it = 0; it < ITERS; ++it) {
        const int t = tid + it * 256;
        if (it < 6 || t < NV4) {
            #pragma unroll
            for (int e = 0; e < 4; ++e)
                __builtin_nontemporal_store(r[it][e], dst + t + e * NV4);
        }
    }
}

extern "C" void kernel_launch(void* const* d_in, const int* in_sizes, int n_in,
                              void* d_out, int out_size, void* d_ws, size_t ws_size,
                              hipStream_t stream) {
    const float* x = (const float*)d_in[0];
    float* out = (float*)d_out;
    const int B = in_sizes[0] / (ADIM * DDIM * GG);   // 32
    const int nblocks = B * ADIM * GDIM;              // 7296 = 8 * 912
    yolo_kernel<<<dim3(nblocks), dim3(256), 0, stream>>>(x, out);
}